// Round 1
// baseline (902.978 us; speedup 1.0000x reference)
//
#include <hip/hip_runtime.h>

typedef __attribute__((ext_vector_type(8))) short short8;
typedef __attribute__((ext_vector_type(4))) float f32x4;

#define CDIM 256
#define NDIM 4096
#define MFMA16(a, b, c) __builtin_amdgcn_mfma_f32_16x16x32_bf16((a), (b), (c), 0, 0, 0)

__device__ __forceinline__ unsigned short f2bf(float x) {
  unsigned u = __builtin_bit_cast(unsigned, x);
  u += 0x7fffu + ((u >> 16) & 1u);   // round-to-nearest-even
  return (unsigned short)(u >> 16);
}
__device__ __forceinline__ float bf2f(unsigned short h) {
  unsigned u = ((unsigned)h) << 16;
  return __builtin_bit_cast(float, u);
}

// ---------------------------------------------------------------------------
// Projection: Y[b,o,n] = sum_c W[o,c] X[b,c,n] + bias[o]
// 3-pass bf16 MFMA (hi/lo split of both operands) -> fp32-accurate result.
// Q,K written transposed as bf16 hi/lo pairs [b][n][c]; V as bf16 [b][c][n].
// ---------------------------------------------------------------------------
__global__ __launch_bounds__(256, 2) void proj_kernel(
    const float* __restrict__ queries, const float* __restrict__ keys,
    const float* __restrict__ Wq, const float* __restrict__ bq,
    const float* __restrict__ Wk, const float* __restrict__ bk,
    const float* __restrict__ Wv, const float* __restrict__ bv,
    unsigned short* __restrict__ Qhi, unsigned short* __restrict__ Qlo,
    unsigned short* __restrict__ Khi, unsigned short* __restrict__ Klo,
    unsigned short* __restrict__ Vb)
{
  const int z = blockIdx.z, p = z >> 3, b = z & 7;
  const float* __restrict__ X = (p == 0) ? queries : keys;
  const float* __restrict__ W = (p == 0) ? Wq : (p == 1 ? Wk : Wv);
  const float* __restrict__ bias = (p == 0) ? bq : (p == 1 ? bk : bv);
  const int o0 = blockIdx.y * 64, n0 = blockIdx.x * 64;

  // stride 40 shorts = 80 B: multiple of 16 B (aligned b128) and bank-spread
  __shared__ __align__(16) unsigned short Wh[64][40];
  __shared__ __align__(16) unsigned short Wl[64][40];
  __shared__ __align__(16) unsigned short Xh[64][40];
  __shared__ __align__(16) unsigned short Xl[64][40];

  const int tid = threadIdx.x;
  const int wv = tid >> 6, lane = tid & 63, l16 = lane & 15, quad = lane >> 4;

  f32x4 acc[4];
#pragma unroll
  for (int s = 0; s < 4; ++s) acc[s] = (f32x4){0.f, 0.f, 0.f, 0.f};

  for (int kc = 0; kc < 8; ++kc) {
    const int c0 = kc * 32;
    __syncthreads();
    {
      const int cc = tid & 31;
#pragma unroll
      for (int it = 0; it < 8; ++it) {
        int oo = (tid >> 5) + it * 8;
        float w = W[(o0 + oo) * CDIM + c0 + cc];
        unsigned short h = f2bf(w);
        Wh[oo][cc] = h;
        Wl[oo][cc] = f2bf(w - bf2f(h));
      }
      const int nn = tid & 63;
#pragma unroll
      for (int it = 0; it < 8; ++it) {
        int cc2 = (tid >> 6) + it * 4;
        float x = X[((size_t)(b * CDIM + c0 + cc2)) * NDIM + n0 + nn];
        unsigned short h = f2bf(x);
        Xh[nn][cc2] = h;
        Xl[nn][cc2] = f2bf(x - bf2f(h));
      }
    }
    __syncthreads();
    short8 wh = *(const short8*)&Wh[wv * 16 + l16][quad * 8];
    short8 wl = *(const short8*)&Wl[wv * 16 + l16][quad * 8];
#pragma unroll
    for (int s = 0; s < 4; ++s) {
      short8 xh = *(const short8*)&Xh[s * 16 + l16][quad * 8];
      short8 xl = *(const short8*)&Xl[s * 16 + l16][quad * 8];
      acc[s] = MFMA16(wh, xh, acc[s]);
      acc[s] = MFMA16(wl, xh, acc[s]);
      acc[s] = MFMA16(wh, xl, acc[s]);
    }
  }

#pragma unroll
  for (int r = 0; r < 4; ++r) {
    const int o = o0 + wv * 16 + quad * 4 + r;
    const float bia = bias[o];
#pragma unroll
    for (int s = 0; s < 4; ++s) {
      const int n = n0 + s * 16 + l16;
      float y = acc[s][r] + bia;
      if (p == 2) {
        Vb[((size_t)(b * CDIM + o)) * NDIM + n] = f2bf(y);
      } else {
        unsigned short h = f2bf(y);
        unsigned short l = f2bf(y - bf2f(h));
        size_t idx = ((size_t)(b * NDIM + n)) * CDIM + o;
        if (p == 0) { Qhi[idx] = h; Qlo[idx] = l; }
        else        { Khi[idx] = h; Klo[idx] = l; }
      }
    }
  }
}

// ---------------------------------------------------------------------------
// Flash attention with row-scaled logits + final mask blend.
// Block: 4 waves, i-tile 64 (16 rows/wave), j-tile 32. 3-pass QK^T, 1-pass PV.
// ---------------------------------------------------------------------------
__global__ __launch_bounds__(256, 2) void attn_kernel(
    const float* __restrict__ queries, const float* __restrict__ mask,
    const unsigned short* __restrict__ Qhi, const unsigned short* __restrict__ Qlo,
    const unsigned short* __restrict__ Khi, const unsigned short* __restrict__ Klo,
    const unsigned short* __restrict__ Vb, float* __restrict__ out)
{
  const int blk = blockIdx.x, b = blk & 7, it = blk >> 3;  // b=blk&7: XCD L2 locality
  const int i0 = it * 64;

  __shared__ __align__(16) unsigned short KsH[32][264];  // [j][c], pad 8
  __shared__ __align__(16) unsigned short KsL[32][264];
  __shared__ __align__(16) unsigned short Vs[256][40];   // [c][j], pad 8
  __shared__ __align__(16) unsigned short Ps[4][16][40]; // per-wave P, [i][j]

  const int tid = threadIdx.x;
  const int wv = tid >> 6, lane = tid & 63, l16 = lane & 15, quad = lane >> 4;

  // Q fragments in registers for the whole kernel (A-layout: m=l16, k=quad*8+t)
  short8 qh[8], ql[8];
  {
    const size_t qrow = ((size_t)(b * NDIM + i0 + wv * 16 + l16)) * CDIM;
#pragma unroll
    for (int kc = 0; kc < 8; ++kc) {
      qh[kc] = *(const short8*)(Qhi + qrow + kc * 32 + quad * 8);
      ql[kc] = *(const short8*)(Qlo + qrow + kc * 32 + quad * 8);
    }
  }
  float mval[4];
#pragma unroll
  for (int r = 0; r < 4; ++r)
    mval[r] = mask[(size_t)b * NDIM + i0 + wv * 16 + quad * 4 + r];

  float m_run[4] = {-1e30f, -1e30f, -1e30f, -1e30f};
  float l_run[4] = {0.f, 0.f, 0.f, 0.f};
  f32x4 O[16];
#pragma unroll
  for (int cc = 0; cc < 16; ++cc) O[cc] = (f32x4){0.f, 0.f, 0.f, 0.f};

  for (int jt = 0; jt < 128; ++jt) {
    const int j0 = jt * 32;
    __syncthreads();
    // stage K hi/lo [32j][256c] and V [256c][32j]
#pragma unroll
    for (int itr = 0; itr < 4; ++itr) {
      int id = tid + itr * 256;
      {
        int r = id >> 5, ch = id & 31;
        size_t src = ((size_t)(b * NDIM + j0 + r)) * CDIM + ch * 8;
        *(uint4*)&KsH[r][ch * 8] = *(const uint4*)(Khi + src);
        *(uint4*)&KsL[r][ch * 8] = *(const uint4*)(Klo + src);
      }
      {
        int c = id >> 2, ch = id & 3;
        size_t src = ((size_t)(b * CDIM + c)) * NDIM + j0 + ch * 8;
        *(uint4*)&Vs[c][ch * 8] = *(const uint4*)(Vb + src);
      }
    }
    __syncthreads();

    // S = Q K^T (3-pass hi/lo), two 16-wide j-subtiles
    f32x4 s0 = (f32x4){0.f, 0.f, 0.f, 0.f}, s1 = (f32x4){0.f, 0.f, 0.f, 0.f};
#pragma unroll
    for (int kc = 0; kc < 8; ++kc) {
      short8 kh0 = *(const short8*)&KsH[l16][kc * 32 + quad * 8];
      short8 kl0 = *(const short8*)&KsL[l16][kc * 32 + quad * 8];
      short8 kh1 = *(const short8*)&KsH[16 + l16][kc * 32 + quad * 8];
      short8 kl1 = *(const short8*)&KsL[16 + l16][kc * 32 + quad * 8];
      s0 = MFMA16(qh[kc], kh0, s0);
      s1 = MFMA16(qh[kc], kh1, s1);
      s0 = MFMA16(ql[kc], kh0, s0);
      s1 = MFMA16(ql[kc], kh1, s1);
      s0 = MFMA16(qh[kc], kl0, s0);
      s1 = MFMA16(qh[kc], kl1, s1);
    }

    // mask-scale + online softmax (rows live in 16-lane groups)
    float alpha[4];
#pragma unroll
    for (int r = 0; r < 4; ++r) {
      float a0 = s0[r] * mval[r];
      float a1 = s1[r] * mval[r];
      float m = fmaxf(a0, a1);
#pragma unroll
      for (int d = 1; d < 16; d <<= 1) m = fmaxf(m, __shfl_xor(m, d));
      float mnew = fmaxf(m_run[r], m);
      alpha[r] = __expf(m_run[r] - mnew);
      m_run[r] = mnew;
      float p0 = __expf(a0 - mnew);
      float p1 = __expf(a1 - mnew);
      Ps[wv][quad * 4 + r][l16] = f2bf(p0);
      Ps[wv][quad * 4 + r][16 + l16] = f2bf(p1);
      float rsum = p0 + p1;
#pragma unroll
      for (int d = 1; d < 16; d <<= 1) rsum += __shfl_xor(rsum, d);
      l_run[r] = l_run[r] * alpha[r] + rsum;
    }
#pragma unroll
    for (int cc = 0; cc < 16; ++cc)
#pragma unroll
      for (int r = 0; r < 4; ++r) O[cc][r] *= alpha[r];

    // O += P V   (P read back in A-layout from this wave's LDS slice)
    short8 pa = *(const short8*)&Ps[wv][l16][quad * 8];
#pragma unroll
    for (int cc = 0; cc < 16; ++cc) {
      short8 vb_ = *(const short8*)&Vs[cc * 16 + l16][quad * 8];
      O[cc] = MFMA16(pa, vb_, O[cc]);
    }
  }

  // epilogue: attn = O/l; out = q*m + (1-m)*attn
  float inv[4];
#pragma unroll
  for (int r = 0; r < 4; ++r) inv[r] = 1.0f / l_run[r];
#pragma unroll
  for (int cc = 0; cc < 16; ++cc) {
    const int c = cc * 16 + l16;
#pragma unroll
    for (int r = 0; r < 4; ++r) {
      const int i = i0 + wv * 16 + quad * 4 + r;
      size_t idx = ((size_t)(b * CDIM + c)) * NDIM + i;
      float attn = O[cc][r] * inv[r];
      float m = mval[r];
      out[idx] = queries[idx] * m + (1.f - m) * attn;
    }
  }
}

extern "C" void kernel_launch(void* const* d_in, const int* in_sizes, int n_in,
                              void* d_out, int out_size, void* d_ws, size_t ws_size,
                              hipStream_t stream) {
  const float* queries = (const float*)d_in[0];
  const float* keys    = (const float*)d_in[1];
  const float* mask    = (const float*)d_in[2];
  const float* Wq = (const float*)d_in[3];
  const float* bq = (const float*)d_in[4];
  const float* Wk = (const float*)d_in[5];
  const float* bk = (const float*)d_in[6];
  const float* Wv = (const float*)d_in[7];
  const float* bv = (const float*)d_in[8];
  float* out = (float*)d_out;

  const size_t elems = (size_t)8 * NDIM * CDIM;  // 8M elements
  unsigned short* Qhi = (unsigned short*)d_ws;
  unsigned short* Qlo = Qhi + elems;
  unsigned short* Khi = Qlo + elems;
  unsigned short* Klo = Khi + elems;
  unsigned short* Vb  = Klo + elems;   // total 80 MB of workspace

  proj_kernel<<<dim3(64, 4, 24), 256, 0, stream>>>(
      queries, keys, Wq, bq, Wk, bk, Wv, bv, Qhi, Qlo, Khi, Klo, Vb);
  attn_kernel<<<dim3(512), 256, 0, stream>>>(
      queries, mask, Qhi, Qlo, Khi, Klo, Vb, out);
}

// Round 2
// 860.878 us; speedup vs baseline: 1.0489x; 1.0489x over previous
//
#include <hip/hip_runtime.h>

typedef __attribute__((ext_vector_type(8))) _Float16 half8;
typedef __attribute__((ext_vector_type(4))) _Float16 half4;
typedef __attribute__((ext_vector_type(4))) float f32x4;

#define CDIM 256
#define NDIM 4096
#define MFMAH(a, b, c) __builtin_amdgcn_mfma_f32_16x16x32_f16((a), (b), (c), 0, 0, 0)

// ---------------------------------------------------------------------------
// Projection: Y[b,o,n] = sum_c W[o,c] X[b,c,n] + bias[o]
// Single-pass fp16 MFMA (fp16 noise ~4e-4 rel, far under fp16 storage ulp).
// Q,K written [b][n][c] fp16 (attention A-operand layout); V as [b][c][n].
// ---------------------------------------------------------------------------
__global__ __launch_bounds__(256, 4) void proj_kernel(
    const float* __restrict__ queries, const float* __restrict__ keys,
    const float* __restrict__ Wq, const float* __restrict__ bq,
    const float* __restrict__ Wk, const float* __restrict__ bk,
    const float* __restrict__ Wv, const float* __restrict__ bv,
    _Float16* __restrict__ Qh, _Float16* __restrict__ Kh,
    _Float16* __restrict__ Vh)
{
  const int z = blockIdx.z, p = z >> 3, b = z & 7;
  const float* __restrict__ X = (p == 0) ? queries : keys;
  const float* __restrict__ W = (p == 0) ? Wq : (p == 1 ? Wk : Wv);
  const float* __restrict__ bias = (p == 0) ? bq : (p == 1 ? bk : bv);
  const int o0 = blockIdx.y * 64, n0 = blockIdx.x * 64;

  __shared__ __align__(16) _Float16 Wh[64][40];  // stride 80 B (16B mult, bank-spread)
  __shared__ __align__(16) _Float16 Xh[64][40];

  const int tid = threadIdx.x;
  const int wv = tid >> 6, lane = tid & 63, l16 = lane & 15, quad = lane >> 4;

  f32x4 acc[4];
#pragma unroll
  for (int s = 0; s < 4; ++s) acc[s] = (f32x4){0.f, 0.f, 0.f, 0.f};

  for (int kc = 0; kc < 8; ++kc) {
    const int c0 = kc * 32;
    __syncthreads();
    // stage W tile 64o x 32c  (float4 loads, half4 stores)
#pragma unroll
    for (int itr = 0; itr < 2; ++itr) {
      int id = tid + itr * 256;
      int o = id >> 3, ch = id & 7;
      float4 w = *(const float4*)&W[(o0 + o) * CDIM + c0 + ch * 4];
      half4 h = {(_Float16)w.x, (_Float16)w.y, (_Float16)w.z, (_Float16)w.w};
      *(half4*)&Wh[o][ch * 4] = h;
    }
    // stage X tile 32c x 64n, transposed into Xh[n][c]
#pragma unroll
    for (int itr = 0; itr < 2; ++itr) {
      int id = tid + itr * 256;
      int c = id >> 4, nch = id & 15;
      float4 x = *(const float4*)&X[((size_t)(b * CDIM + c0 + c)) * NDIM + n0 + nch * 4];
      Xh[nch * 4 + 0][c] = (_Float16)x.x;
      Xh[nch * 4 + 1][c] = (_Float16)x.y;
      Xh[nch * 4 + 2][c] = (_Float16)x.z;
      Xh[nch * 4 + 3][c] = (_Float16)x.w;
    }
    __syncthreads();
    half8 wf = *(const half8*)&Wh[wv * 16 + l16][quad * 8];
#pragma unroll
    for (int s = 0; s < 4; ++s) {
      half8 xf = *(const half8*)&Xh[s * 16 + l16][quad * 8];
      acc[s] = MFMAH(wf, xf, acc[s]);
    }
  }

#pragma unroll
  for (int r = 0; r < 4; ++r) {
    const int o = o0 + wv * 16 + quad * 4 + r;
    const float bia = bias[o];
#pragma unroll
    for (int s = 0; s < 4; ++s) {
      const int n = n0 + s * 16 + l16;
      float y = acc[s][r] + bia;
      if (p == 2) {
        Vh[((size_t)(b * CDIM + o)) * NDIM + n] = (_Float16)y;
      } else {
        size_t idx = ((size_t)(b * NDIM + n)) * CDIM + o;
        if (p == 0) Qh[idx] = (_Float16)y;
        else        Kh[idx] = (_Float16)y;
      }
    }
  }
}

// ---------------------------------------------------------------------------
// Flash attention, single-pass fp16 QK^T and PV, register-prefetched staging.
// Block: 4 waves, i-tile 64 (16 rows/wave), j-tile 32. LDS 42.5 KB -> 3 blk/CU.
// ---------------------------------------------------------------------------
__global__ __launch_bounds__(256, 3) void attn_kernel(
    const float* __restrict__ queries, const float* __restrict__ mask,
    const _Float16* __restrict__ Qh, const _Float16* __restrict__ Kh,
    const _Float16* __restrict__ Vh, float* __restrict__ out)
{
  const int blk = blockIdx.x, b = blk & 7, it = blk >> 3;  // b=blk&7: XCD L2 locality
  const int i0 = it * 64;

  __shared__ __align__(16) _Float16 Ks[32][264];  // [j][c], pad 8 (stride 528 B)
  __shared__ __align__(16) _Float16 Vs[256][40];  // [c][j], pad 8 (stride 80 B)
  __shared__ __align__(16) _Float16 Ps[4][16][40];

  const int tid = threadIdx.x;
  const int wv = tid >> 6, lane = tid & 63, l16 = lane & 15, quad = lane >> 4;

  // Q fragments in registers for the whole kernel (A-layout: m=l16, k=quad*8+t)
  half8 qf[8];
  {
    const size_t qrow = ((size_t)(b * NDIM + i0 + wv * 16 + l16)) * CDIM;
#pragma unroll
    for (int kc = 0; kc < 8; ++kc)
      qf[kc] = *(const half8*)(Qh + qrow + kc * 32 + quad * 8);
  }
  float mval[4];
#pragma unroll
  for (int r = 0; r < 4; ++r)
    mval[r] = mask[(size_t)b * NDIM + i0 + wv * 16 + quad * 4 + r];

  float m_run[4] = {-1e30f, -1e30f, -1e30f, -1e30f};
  float l_run[4] = {0.f, 0.f, 0.f, 0.f};
  f32x4 O[16];
#pragma unroll
  for (int cc = 0; cc < 16; ++cc) O[cc] = (f32x4){0.f, 0.f, 0.f, 0.f};

  uint4 pk[4], pv[4];
  // prefetch lambda: load K/V tile for key-block starting at j0 into regs
  auto prefetch = [&](int j0) {
#pragma unroll
    for (int itr = 0; itr < 4; ++itr) {
      int id = tid + itr * 256;
      pk[itr] = *(const uint4*)(Kh + ((size_t)(b * NDIM + j0 + (id >> 5))) * CDIM + (id & 31) * 8);
      pv[itr] = *(const uint4*)(Vh + ((size_t)(b * CDIM + (id >> 2))) * NDIM + j0 + (id & 3) * 8);
    }
  };
  auto commit = [&]() {
#pragma unroll
    for (int itr = 0; itr < 4; ++itr) {
      int id = tid + itr * 256;
      *(uint4*)&Ks[id >> 5][(id & 31) * 8] = pk[itr];
      *(uint4*)&Vs[id >> 2][(id & 3) * 8] = pv[itr];
    }
  };

  prefetch(0);
  commit();
  __syncthreads();

  for (int jt = 0; jt < 128; ++jt) {
    if (jt < 127) prefetch((jt + 1) * 32);  // hide global latency behind compute

    // S = Q K^T, two 16-wide j-subtiles
    f32x4 s0 = (f32x4){0.f, 0.f, 0.f, 0.f}, s1 = (f32x4){0.f, 0.f, 0.f, 0.f};
#pragma unroll
    for (int kc = 0; kc < 8; ++kc) {
      half8 k0 = *(const half8*)&Ks[l16][kc * 32 + quad * 8];
      half8 k1 = *(const half8*)&Ks[16 + l16][kc * 32 + quad * 8];
      s0 = MFMAH(qf[kc], k0, s0);
      s1 = MFMAH(qf[kc], k1, s1);
    }

    // mask-scale + online softmax (rows live in 16-lane groups)
    float alpha[4];
#pragma unroll
    for (int r = 0; r < 4; ++r) {
      float a0 = s0[r] * mval[r];
      float a1 = s1[r] * mval[r];
      float m = fmaxf(a0, a1);
#pragma unroll
      for (int d = 1; d < 16; d <<= 1) m = fmaxf(m, __shfl_xor(m, d));
      float mnew = fmaxf(m_run[r], m);
      alpha[r] = __expf(m_run[r] - mnew);
      m_run[r] = mnew;
      float p0 = __expf(a0 - mnew);
      float p1 = __expf(a1 - mnew);
      Ps[wv][quad * 4 + r][l16] = (_Float16)p0;
      Ps[wv][quad * 4 + r][16 + l16] = (_Float16)p1;
      float rsum = p0 + p1;
#pragma unroll
      for (int d = 1; d < 16; d <<= 1) rsum += __shfl_xor(rsum, d);
      l_run[r] = l_run[r] * alpha[r] + rsum;
    }
#pragma unroll
    for (int cc = 0; cc < 16; ++cc)
#pragma unroll
      for (int r = 0; r < 4; ++r) O[cc][r] *= alpha[r];

    // O += P V   (P read back in A-layout from this wave's LDS slice)
    half8 pa = *(const half8*)&Ps[wv][l16][quad * 8];
#pragma unroll
    for (int cc = 0; cc < 16; ++cc) {
      half8 vf = *(const half8*)&Vs[cc * 16 + l16][quad * 8];
      O[cc] = MFMAH(pa, vf, O[cc]);
    }

    __syncthreads();
    if (jt < 127) commit();
    __syncthreads();
  }

  // epilogue: attn = O/l; out = q*m + (1-m)*attn   (float4 along i)
  float inv[4];
#pragma unroll
  for (int r = 0; r < 4; ++r) inv[r] = 1.0f / l_run[r];
#pragma unroll
  for (int cc = 0; cc < 16; ++cc) {
    const int c = cc * 16 + l16;
    const size_t base = ((size_t)(b * CDIM + c)) * NDIM + i0 + wv * 16 + quad * 4;
    float4 q4 = *(const float4*)(queries + base);
    float4 o4;
    o4.x = q4.x * mval[0] + (1.f - mval[0]) * (O[cc][0] * inv[0]);
    o4.y = q4.y * mval[1] + (1.f - mval[1]) * (O[cc][1] * inv[1]);
    o4.z = q4.z * mval[2] + (1.f - mval[2]) * (O[cc][2] * inv[2]);
    o4.w = q4.w * mval[3] + (1.f - mval[3]) * (O[cc][3] * inv[3]);
    *(float4*)(out + base) = o4;
  }
}

extern "C" void kernel_launch(void* const* d_in, const int* in_sizes, int n_in,
                              void* d_out, int out_size, void* d_ws, size_t ws_size,
                              hipStream_t stream) {
  const float* queries = (const float*)d_in[0];
  const float* keys    = (const float*)d_in[1];
  const float* mask    = (const float*)d_in[2];
  const float* Wq = (const float*)d_in[3];
  const float* bq = (const float*)d_in[4];
  const float* Wk = (const float*)d_in[5];
  const float* bk = (const float*)d_in[6];
  const float* Wv = (const float*)d_in[7];
  const float* bv = (const float*)d_in[8];
  float* out = (float*)d_out;

  const size_t elems = (size_t)8 * NDIM * CDIM;  // 8.4M elements
  _Float16* Qh = (_Float16*)d_ws;
  _Float16* Kh = Qh + elems;
  _Float16* Vh = Kh + elems;   // total ~50 MB of workspace

  proj_kernel<<<dim3(64, 4, 24), 256, 0, stream>>>(
      queries, keys, Wq, bq, Wk, bk, Wv, bv, Qh, Kh, Vh);
  attn_kernel<<<dim3(512), 256, 0, stream>>>(
      queries, mask, Qh, Kh, Vh, out);
}

// Round 3
// 415.969 us; speedup vs baseline: 2.1708x; 2.0696x over previous
//
#include <hip/hip_runtime.h>

typedef __attribute__((ext_vector_type(8))) _Float16 half8;
typedef __attribute__((ext_vector_type(4))) _Float16 half4;
typedef __attribute__((ext_vector_type(4))) float f32x4;

#define CDIM 256
#define NDIM 4096
#define MFMAH(a, b, c) __builtin_amdgcn_mfma_f32_16x16x32_f16((a), (b), (c), 0, 0, 0)

// ---------------------------------------------------------------------------
// Projection: Y[b,o,n] = sum_c W[o,c] X[b,c,n] + bias[o]
// o-tile = 256 (full) so the X tile is staged ONCE per n-tile (was 4x HBM).
// Q,K written [b][n][c] fp16 (attention A/B layout); V as [b][c][n].
// ---------------------------------------------------------------------------
__global__ __launch_bounds__(256, 2) void proj_kernel(
    const float* __restrict__ queries, const float* __restrict__ keys,
    const float* __restrict__ Wq, const float* __restrict__ bq,
    const float* __restrict__ Wk, const float* __restrict__ bk,
    const float* __restrict__ Wv, const float* __restrict__ bv,
    _Float16* __restrict__ Qh, _Float16* __restrict__ Kh,
    _Float16* __restrict__ Vh)
{
  const int z = blockIdx.z, p = z >> 3, b = z & 7;
  const float* __restrict__ X = (p == 0) ? queries : keys;
  const float* __restrict__ W = (p == 0) ? Wq : (p == 1 ? Wk : Wv);
  const float* __restrict__ bias = (p == 0) ? bq : (p == 1 ? bk : bv);
  const int n0 = blockIdx.x * 64;

  __shared__ __align__(16) _Float16 Xs[64][264];  // [n][c], stride 528 B (16B mult, 2-way banks)
  __shared__ __align__(16) _Float16 Ws[256][40];  // [o][cc] per-kc, stride 80 B

  const int tid = threadIdx.x;
  const int wv = tid >> 6, lane = tid & 63, l16 = lane & 15, quad = lane >> 4;

  // stage full X tile once: 64 n x 256 c  (transpose c-major -> Xs[n][c])
#pragma unroll
  for (int it = 0; it < 16; ++it) {
    int id = tid + it * 256;
    int c = id >> 4, n4 = id & 15;
    float4 x = *(const float4*)&X[((size_t)(b * CDIM + c)) * NDIM + n0 + n4 * 4];
    Xs[n4 * 4 + 0][c] = (_Float16)x.x;
    Xs[n4 * 4 + 1][c] = (_Float16)x.y;
    Xs[n4 * 4 + 2][c] = (_Float16)x.z;
    Xs[n4 * 4 + 3][c] = (_Float16)x.w;
  }

  f32x4 acc[4][4];
#pragma unroll
  for (int og = 0; og < 4; ++og)
#pragma unroll
    for (int ng = 0; ng < 4; ++ng) acc[og][ng] = (f32x4){0.f, 0.f, 0.f, 0.f};

  for (int kc = 0; kc < 8; ++kc) {
    __syncthreads();
    // stage W strip: 256 o x 32 c
#pragma unroll
    for (int it = 0; it < 8; ++it) {
      int id = tid + it * 256;
      int o = id >> 3, c4 = id & 7;
      float4 w = *(const float4*)&W[o * CDIM + kc * 32 + c4 * 4];
      half4 h = {(_Float16)w.x, (_Float16)w.y, (_Float16)w.z, (_Float16)w.w};
      *(half4*)&Ws[o][c4 * 4] = h;
    }
    __syncthreads();
    half8 wf[4], xf[4];
#pragma unroll
    for (int og = 0; og < 4; ++og)
      wf[og] = *(const half8*)&Ws[wv * 64 + og * 16 + l16][quad * 8];
#pragma unroll
    for (int ng = 0; ng < 4; ++ng)
      xf[ng] = *(const half8*)&Xs[ng * 16 + l16][kc * 32 + quad * 8];
#pragma unroll
    for (int og = 0; og < 4; ++og)
#pragma unroll
      for (int ng = 0; ng < 4; ++ng)
        acc[og][ng] = MFMAH(wf[og], xf[ng], acc[og][ng]);
  }

  // epilogue
#pragma unroll
  for (int og = 0; og < 4; ++og) {
    float4 b4 = *(const float4*)&bias[wv * 64 + og * 16 + quad * 4];
#pragma unroll
    for (int ng = 0; ng < 4; ++ng) {
      const int n = n0 + ng * 16 + l16;
      if (p == 2) {
#pragma unroll
        for (int r = 0; r < 4; ++r) {
          int o = wv * 64 + og * 16 + quad * 4 + r;
          float y = acc[og][ng][r] + ((const float*)&b4)[r];
          Vh[((size_t)(b * CDIM + o)) * NDIM + n] = (_Float16)y;
        }
      } else {
        half4 h4;
#pragma unroll
        for (int r = 0; r < 4; ++r)
          h4[r] = (_Float16)(acc[og][ng][r] + ((const float*)&b4)[r]);
        size_t idx = ((size_t)(b * NDIM + n)) * CDIM + wv * 64 + og * 16 + quad * 4;
        if (p == 0) *(half4*)&Qh[idx] = h4;
        else        *(half4*)&Kh[idx] = h4;
      }
    }
  }
}

// ---------------------------------------------------------------------------
// Flash attention. i-tile 64, j-tile 64, 4 waves.
// QK: wave owns 16 i-rows, all 64 j (32 MFMA, 32 K-frag reads).
// PV: wave owns 64 channels, all 64 i  -> each P/V frag feeds 4 MFMAs.
// alpha / 1/l shared across waves via tiny LDS arrays. 3 barriers per j-tile.
// ---------------------------------------------------------------------------
__global__ __launch_bounds__(256, 2) void attn_kernel(
    const float* __restrict__ queries, const float* __restrict__ mask,
    const _Float16* __restrict__ Qh, const _Float16* __restrict__ Kh,
    const _Float16* __restrict__ Vh, float* __restrict__ out)
{
  const int blk = blockIdx.x, b = blk & 7, it = blk >> 3;  // b=blk&7: XCD L2 locality
  const int i0 = it * 64;

  __shared__ __align__(16) _Float16 Ks[64][264];  // [j][c]  33792 B
  __shared__ __align__(16) _Float16 Vs[256][72];  // [c][j]  36864 B
  __shared__ __align__(16) _Float16 Ps[64][72];   // [i][j]   9216 B
  __shared__ __align__(16) float Al[64];          // alpha per i-row
  __shared__ __align__(16) float Li[64];          // 1/l per i-row

  const int tid = threadIdx.x;
  const int wv = tid >> 6, lane = tid & 63, l16 = lane & 15, quad = lane >> 4;

  // Q fragments (A-layout: m=l16 row, k=quad*8+t) for this wave's 16 rows
  half8 qf[8];
  {
    const size_t qrow = ((size_t)(b * NDIM + i0 + wv * 16 + l16)) * CDIM;
#pragma unroll
    for (int kc = 0; kc < 8; ++kc)
      qf[kc] = *(const half8*)(Qh + qrow + kc * 32 + quad * 8);
  }
  float mval[4];
#pragma unroll
  for (int r = 0; r < 4; ++r)
    mval[r] = mask[(size_t)b * NDIM + i0 + wv * 16 + quad * 4 + r];

  float m_run[4] = {-1e30f, -1e30f, -1e30f, -1e30f};
  float l_run[4] = {0.f, 0.f, 0.f, 0.f};
  f32x4 O[4][4];  // [i-group][ch-group], wave's ch base = wv*64
#pragma unroll
  for (int g = 0; g < 4; ++g)
#pragma unroll
    for (int cg = 0; cg < 4; ++cg) O[g][cg] = (f32x4){0.f, 0.f, 0.f, 0.f};

  const _Float16* __restrict__ Kb = Kh + (size_t)b * NDIM * CDIM;
  const _Float16* __restrict__ Vbp = Vh + (size_t)b * CDIM * NDIM;

  for (int jt = 0; jt < 64; ++jt) {
    const int j0 = jt * 64;
    __syncthreads();  // prev iter's Ks/Vs/Ps/Al reads complete
    // stage K 64x256 and V 256x64 (transient regs, no live-across-compute)
#pragma unroll
    for (int it2 = 0; it2 < 8; ++it2) {
      int id = tid + it2 * 256;
      int j = id >> 5, c8 = id & 31;
      *(uint4*)&Ks[j][c8 * 8] = *(const uint4*)(Kb + (size_t)(j0 + j) * CDIM + c8 * 8);
    }
#pragma unroll
    for (int it2 = 0; it2 < 8; ++it2) {
      int id = tid + it2 * 256;
      int c = id >> 3, j8 = id & 7;
      *(uint4*)&Vs[c][j8 * 8] = *(const uint4*)(Vbp + (size_t)c * NDIM + j0 + j8 * 8);
    }
    __syncthreads();

    // S = Q K^T over 4 j-subtiles
    f32x4 s[4];
#pragma unroll
    for (int js = 0; js < 4; ++js) s[js] = (f32x4){0.f, 0.f, 0.f, 0.f};
#pragma unroll
    for (int kc = 0; kc < 8; ++kc) {
#pragma unroll
      for (int js = 0; js < 4; ++js) {
        half8 kf = *(const half8*)&Ks[js * 16 + l16][kc * 32 + quad * 8];
        s[js] = MFMAH(qf[kc], kf, s[js]);
      }
    }

    // online softmax; row i = wv*16 + quad*4 + r lives in 16-lane group l16
    float alpha[4];
#pragma unroll
    for (int r = 0; r < 4; ++r) {
      float a0 = s[0][r] * mval[r], a1 = s[1][r] * mval[r];
      float a2 = s[2][r] * mval[r], a3 = s[3][r] * mval[r];
      float mloc = fmaxf(fmaxf(a0, a1), fmaxf(a2, a3));
#pragma unroll
      for (int d = 1; d < 16; d <<= 1) mloc = fmaxf(mloc, __shfl_xor(mloc, d));
      float mnew = fmaxf(m_run[r], mloc);
      alpha[r] = __expf(m_run[r] - mnew);
      m_run[r] = mnew;
      float p0 = __expf(a0 - mnew), p1 = __expf(a1 - mnew);
      float p2 = __expf(a2 - mnew), p3 = __expf(a3 - mnew);
      const int row = wv * 16 + quad * 4 + r;
      Ps[row][l16] = (_Float16)p0;
      Ps[row][16 + l16] = (_Float16)p1;
      Ps[row][32 + l16] = (_Float16)p2;
      Ps[row][48 + l16] = (_Float16)p3;
      float rs = p0 + p1 + p2 + p3;
#pragma unroll
      for (int d = 1; d < 16; d <<= 1) rs += __shfl_xor(rs, d);
      l_run[r] = l_run[r] * alpha[r] + rs;
    }
    if (l16 == 0) {
#pragma unroll
      for (int r = 0; r < 4; ++r) Al[wv * 16 + quad * 4 + r] = alpha[r];
    }
    __syncthreads();

    // O rescale + O += P V  (wave covers all 64 i, channels [wv*64, wv*64+64))
    f32x4 av[4];
#pragma unroll
    for (int g = 0; g < 4; ++g) av[g] = *(const f32x4*)&Al[g * 16 + quad * 4];
#pragma unroll
    for (int g = 0; g < 4; ++g)
#pragma unroll
      for (int cg = 0; cg < 4; ++cg)
#pragma unroll
        for (int r = 0; r < 4; ++r) O[g][cg][r] *= av[g][r];
#pragma unroll
    for (int kk = 0; kk < 2; ++kk) {
      half8 pa[4], vf[4];
#pragma unroll
      for (int g = 0; g < 4; ++g)
        pa[g] = *(const half8*)&Ps[g * 16 + l16][kk * 32 + quad * 8];
#pragma unroll
      for (int cg = 0; cg < 4; ++cg)
        vf[cg] = *(const half8*)&Vs[wv * 64 + cg * 16 + l16][kk * 32 + quad * 8];
#pragma unroll
      for (int g = 0; g < 4; ++g)
#pragma unroll
        for (int cg = 0; cg < 4; ++cg)
          O[g][cg] = MFMAH(pa[g], vf[cg], O[g][cg]);
    }
  }

  // publish 1/l, then blended epilogue
  if (l16 == 0) {
#pragma unroll
    for (int r = 0; r < 4; ++r) Li[wv * 16 + quad * 4 + r] = 1.0f / l_run[r];
  }
  __syncthreads();
#pragma unroll
  for (int g = 0; g < 4; ++g) {
    f32x4 li4 = *(const f32x4*)&Li[g * 16 + quad * 4];
    const int i = i0 + g * 16 + quad * 4;
    float4 m4 = *(const float4*)&mask[(size_t)b * NDIM + i];
#pragma unroll
    for (int cg = 0; cg < 4; ++cg) {
      const int c = wv * 64 + cg * 16 + l16;
      const size_t base = ((size_t)(b * CDIM + c)) * NDIM + i;
      float4 q4 = *(const float4*)(queries + base);
      float4 o4;
      o4.x = q4.x * m4.x + (1.f - m4.x) * (O[g][cg][0] * li4[0]);
      o4.y = q4.y * m4.y + (1.f - m4.y) * (O[g][cg][1] * li4[1]);
      o4.z = q4.z * m4.z + (1.f - m4.z) * (O[g][cg][2] * li4[2]);
      o4.w = q4.w * m4.w + (1.f - m4.w) * (O[g][cg][3] * li4[3]);
      *(float4*)(out + base) = o4;
    }
  }
}

extern "C" void kernel_launch(void* const* d_in, const int* in_sizes, int n_in,
                              void* d_out, int out_size, void* d_ws, size_t ws_size,
                              hipStream_t stream) {
  const float* queries = (const float*)d_in[0];
  const float* keys    = (const float*)d_in[1];
  const float* mask    = (const float*)d_in[2];
  const float* Wq = (const float*)d_in[3];
  const float* bq = (const float*)d_in[4];
  const float* Wk = (const float*)d_in[5];
  const float* bk = (const float*)d_in[6];
  const float* Wv = (const float*)d_in[7];
  const float* bv = (const float*)d_in[8];
  float* out = (float*)d_out;

  const size_t elems = (size_t)8 * NDIM * CDIM;
  _Float16* Qh = (_Float16*)d_ws;
  _Float16* Kh = Qh + elems;
  _Float16* Vh = Kh + elems;

  proj_kernel<<<dim3(64, 1, 24), 256, 0, stream>>>(
      queries, keys, Wq, bq, Wk, bk, Wv, bv, Qh, Kh, Vh);
  attn_kernel<<<dim3(512), 256, 0, stream>>>(
      queries, mask, Qh, Kh, Vh, out);
}

// Round 5
// 358.618 us; speedup vs baseline: 2.5179x; 1.1599x over previous
//
#include <hip/hip_runtime.h>

typedef __attribute__((ext_vector_type(8))) _Float16 half8;
typedef __attribute__((ext_vector_type(4))) _Float16 half4;
typedef __attribute__((ext_vector_type(4))) float f32x4;

#define CDIM 256
#define NDIM 4096
#define MFMAH(a, b, c) __builtin_amdgcn_mfma_f32_16x16x32_f16((a), (b), (c), 0, 0, 0)

// ---------------------------------------------------------------------------
// Cast W matrices to fp16 once per launch (L2-resident afterwards).
// ---------------------------------------------------------------------------
__global__ void cast_w_kernel(const float* __restrict__ Wq,
                              const float* __restrict__ Wk,
                              const float* __restrict__ Wv,
                              _Float16* __restrict__ Wc) {
  int t = blockIdx.x * 256 + threadIdx.x;      // 49152 float4 groups total
  int mat = t >> 14;                            // /16384
  int idx = (t & 16383) * 4;
  const float* W = (mat == 0) ? Wq : (mat == 1 ? Wk : Wv);
  float4 w = *(const float4*)(W + idx);
  half4 h = {(_Float16)w.x, (_Float16)w.y, (_Float16)w.z, (_Float16)w.w};
  *(half4*)(Wc + mat * 65536 + idx) = h;
}

// ---------------------------------------------------------------------------
// Projection: Y[b,o,n] = sum_c W[o,c] X[b,c,n] + bias[o]
// n-tile 128, full o (256). X staged once (no per-kc barriers); W-frags read
// directly from global fp16 (L2-hot). Q,K -> [b][n][c]; V -> [b][c][n].
// ---------------------------------------------------------------------------
__global__ __launch_bounds__(256, 2) void proj_kernel(
    const float* __restrict__ queries, const float* __restrict__ keys,
    const _Float16* __restrict__ Wc,
    const float* __restrict__ bq, const float* __restrict__ bk,
    const float* __restrict__ bv,
    _Float16* __restrict__ Qh, _Float16* __restrict__ Kh,
    _Float16* __restrict__ Vh)
{
  const int z = blockIdx.z, p = z >> 3, b = z & 7;
  const float* __restrict__ X = (p == 0) ? queries : keys;
  const _Float16* __restrict__ W = Wc + p * 65536;
  const float* __restrict__ bias = (p == 0) ? bq : (p == 1 ? bk : bv);
  const int n0 = blockIdx.x * 128;

  __shared__ __align__(16) _Float16 Xs[128][264];  // [n][c], 528 B rows

  const int tid = threadIdx.x;
  const int wv = tid >> 6, lane = tid & 63, l16 = lane & 15, quad = lane >> 4;

  // stage X tile 128n x 256c (transpose c-major global -> Xs[n][c])
#pragma unroll
  for (int it = 0; it < 32; ++it) {
    int id = tid + it * 256;
    int c = id >> 5, n4 = id & 31;
    float4 x = *(const float4*)&X[((size_t)(b * CDIM + c)) * NDIM + n0 + n4 * 4];
    Xs[n4 * 4 + 0][c] = (_Float16)x.x;
    Xs[n4 * 4 + 1][c] = (_Float16)x.y;
    Xs[n4 * 4 + 2][c] = (_Float16)x.z;
    Xs[n4 * 4 + 3][c] = (_Float16)x.w;
  }
  __syncthreads();

  f32x4 acc[4][8];
#pragma unroll
  for (int og = 0; og < 4; ++og)
#pragma unroll
    for (int ng = 0; ng < 8; ++ng) acc[og][ng] = (f32x4){0.f, 0.f, 0.f, 0.f};

#pragma unroll
  for (int kc = 0; kc < 8; ++kc) {
    half8 wf[4], xf[8];
#pragma unroll
    for (int og = 0; og < 4; ++og)
      wf[og] = *(const half8*)(W + (wv * 64 + og * 16 + l16) * CDIM + kc * 32 + quad * 8);
#pragma unroll
    for (int ng = 0; ng < 8; ++ng)
      xf[ng] = *(const half8*)&Xs[ng * 16 + l16][kc * 32 + quad * 8];
#pragma unroll
    for (int og = 0; og < 4; ++og)
#pragma unroll
      for (int ng = 0; ng < 8; ++ng)
        acc[og][ng] = MFMAH(wf[og], xf[ng], acc[og][ng]);
  }

  // epilogue: D rows = o (quad*4+r), cols = n (l16)
#pragma unroll
  for (int og = 0; og < 4; ++og) {
    float4 b4 = *(const float4*)&bias[wv * 64 + og * 16 + quad * 4];
#pragma unroll
    for (int ng = 0; ng < 8; ++ng) {
      const int n = n0 + ng * 16 + l16;
      if (p == 2) {
#pragma unroll
        for (int r = 0; r < 4; ++r) {
          int o = wv * 64 + og * 16 + quad * 4 + r;
          float y = acc[og][ng][r] + ((const float*)&b4)[r];
          Vh[((size_t)(b * CDIM + o)) * NDIM + n] = (_Float16)y;
        }
      } else {
        half4 h4;
#pragma unroll
        for (int r = 0; r < 4; ++r)
          h4[r] = (_Float16)(acc[og][ng][r] + ((const float*)&b4)[r]);
        size_t idx = ((size_t)(b * NDIM + n)) * CDIM + wv * 64 + og * 16 + quad * 4;
        if (p == 0) *(half4*)&Qh[idx] = h4;
        else        *(half4*)&Kh[idx] = h4;
      }
    }
  }
}

// ---------------------------------------------------------------------------
// Flash attention, S-TRANSPOSED QK (A=K, B=Q): lane owns ONE i-row in softmax
// -> in-lane reductions (2 shuffles), packed b64 Ps writes. PV unchanged.
// ---------------------------------------------------------------------------
__global__ __launch_bounds__(256, 2) void attn_kernel(
    const float* __restrict__ queries, const float* __restrict__ mask,
    const _Float16* __restrict__ Qh, const _Float16* __restrict__ Kh,
    const _Float16* __restrict__ Vh, float* __restrict__ out)
{
  const int blk = blockIdx.x, b = blk & 7, it = blk >> 3;  // b=blk&7: XCD L2 locality
  const int i0 = it * 64;

  __shared__ __align__(16) _Float16 Ks[64][264];  // [j][c]  33792 B
  __shared__ __align__(16) _Float16 Vs[256][72];  // [c][j]  36864 B
  __shared__ __align__(16) _Float16 Ps[64][72];   // [i][j]   9216 B
  __shared__ __align__(16) float Al[64];          // alpha per i-row
  __shared__ __align__(16) float Li[64];          // 1/l per i-row

  const int tid = threadIdx.x;
  const int wv = tid >> 6, lane = tid & 63, l16 = lane & 15, quad = lane >> 4;

  // Q fragments: B-operand layout (n=l16 -> i-row, k=quad*8+t -> c) — same
  // bytes as the A-layout load, role-swapped into the MFMA.
  half8 qf[8];
  {
    const size_t qrow = ((size_t)(b * NDIM + i0 + wv * 16 + l16)) * CDIM;
#pragma unroll
    for (int kc = 0; kc < 8; ++kc)
      qf[kc] = *(const half8*)(Qh + qrow + kc * 32 + quad * 8);
  }
  // per-lane softmax state: this lane's i-row is i0 + wv*16 + l16
  const float mval = mask[(size_t)b * NDIM + i0 + wv * 16 + l16];
  float m_run = -1e30f, l_run = 0.f;

  f32x4 O[4][4];  // [i-group][ch-group], wave's ch base = wv*64
#pragma unroll
  for (int g = 0; g < 4; ++g)
#pragma unroll
    for (int cg = 0; cg < 4; ++cg) O[g][cg] = (f32x4){0.f, 0.f, 0.f, 0.f};

  const _Float16* __restrict__ Kb = Kh + (size_t)b * NDIM * CDIM;
  const _Float16* __restrict__ Vbp = Vh + (size_t)b * CDIM * NDIM;

  for (int jt = 0; jt < 64; ++jt) {
    const int j0 = jt * 64;
    __syncthreads();  // prev iter's Ks/Vs/Ps/Al reads complete
#pragma unroll
    for (int it2 = 0; it2 < 8; ++it2) {
      int id = tid + it2 * 256;
      int j = id >> 5, c8 = id & 31;
      *(uint4*)&Ks[j][c8 * 8] = *(const uint4*)(Kb + (size_t)(j0 + j) * CDIM + c8 * 8);
    }
#pragma unroll
    for (int it2 = 0; it2 < 8; ++it2) {
      int id = tid + it2 * 256;
      int c = id >> 3, j8 = id & 7;
      *(uint4*)&Vs[c][j8 * 8] = *(const uint4*)(Vbp + (size_t)c * NDIM + j0 + j8 * 8);
    }
    __syncthreads();

    // S^T = K Q^T: D[m=j][n=i]; lane holds 16 j-values for i = wv*16+l16
    f32x4 s[4];
#pragma unroll
    for (int js = 0; js < 4; ++js) s[js] = (f32x4){0.f, 0.f, 0.f, 0.f};
#pragma unroll
    for (int kc = 0; kc < 8; ++kc) {
#pragma unroll
      for (int js = 0; js < 4; ++js) {
        half8 kf = *(const half8*)&Ks[js * 16 + l16][kc * 32 + quad * 8];
        s[js] = MFMAH(kf, qf[kc], s[js]);
      }
    }

    // online softmax, in-lane over 16 j-values + cross-quad (xor16, xor32)
    float a[16];
    float mx = -1e30f;
#pragma unroll
    for (int js = 0; js < 4; ++js)
#pragma unroll
      for (int r = 0; r < 4; ++r) {
        float v = s[js][r] * mval;
        a[js * 4 + r] = v;
        mx = fmaxf(mx, v);
      }
    mx = fmaxf(mx, __shfl_xor(mx, 16));
    mx = fmaxf(mx, __shfl_xor(mx, 32));
    const float mnew = fmaxf(m_run, mx);
    const float alpha = __expf(m_run - mnew);
    m_run = mnew;
    float psum = 0.f;
#pragma unroll
    for (int js = 0; js < 4; ++js) {
      float p0 = __expf(a[js * 4 + 0] - mnew);
      float p1 = __expf(a[js * 4 + 1] - mnew);
      float p2 = __expf(a[js * 4 + 2] - mnew);
      float p3 = __expf(a[js * 4 + 3] - mnew);
      psum += (p0 + p1) + (p2 + p3);
      half4 hp = {(_Float16)p0, (_Float16)p1, (_Float16)p2, (_Float16)p3};
      // P[i][j]: i = wv*16+l16, j = js*16 + quad*4 + r  (j-contiguous pack)
      *(half4*)&Ps[wv * 16 + l16][js * 16 + quad * 4] = hp;
    }
    psum += __shfl_xor(psum, 16);
    psum += __shfl_xor(psum, 32);
    l_run = l_run * alpha + psum;
    if (quad == 0) Al[wv * 16 + l16] = alpha;
    __syncthreads();

    // O rescale + O += P V  (wave covers all 64 i, channels [wv*64, +64))
    f32x4 av[4];
#pragma unroll
    for (int g = 0; g < 4; ++g) av[g] = *(const f32x4*)&Al[g * 16 + quad * 4];
#pragma unroll
    for (int g = 0; g < 4; ++g)
#pragma unroll
      for (int cg = 0; cg < 4; ++cg)
#pragma unroll
        for (int r = 0; r < 4; ++r) O[g][cg][r] *= av[g][r];
#pragma unroll
    for (int kk = 0; kk < 2; ++kk) {
      half8 pa[4], vf[4];
#pragma unroll
      for (int g = 0; g < 4; ++g)
        pa[g] = *(const half8*)&Ps[g * 16 + l16][kk * 32 + quad * 8];
#pragma unroll
      for (int cg = 0; cg < 4; ++cg)
        vf[cg] = *(const half8*)&Vs[wv * 64 + cg * 16 + l16][kk * 32 + quad * 8];
#pragma unroll
      for (int g = 0; g < 4; ++g)
#pragma unroll
        for (int cg = 0; cg < 4; ++cg)
          O[g][cg] = MFMAH(pa[g], vf[cg], O[g][cg]);
    }
  }

  // publish 1/l, then blended epilogue
  if (quad == 0) Li[wv * 16 + l16] = 1.0f / l_run;
  __syncthreads();
#pragma unroll
  for (int g = 0; g < 4; ++g) {
    f32x4 li4 = *(const f32x4*)&Li[g * 16 + quad * 4];
    const int i = i0 + g * 16 + quad * 4;
    float4 m4 = *(const float4*)&mask[(size_t)b * NDIM + i];
#pragma unroll
    for (int cg = 0; cg < 4; ++cg) {
      const int c = wv * 64 + cg * 16 + l16;
      const size_t base = ((size_t)(b * CDIM + c)) * NDIM + i;
      float4 q4 = *(const float4*)(queries + base);
      float4 o4;
      o4.x = q4.x * m4.x + (1.f - m4.x) * (O[g][cg][0] * li4[0]);
      o4.y = q4.y * m4.y + (1.f - m4.y) * (O[g][cg][1] * li4[1]);
      o4.z = q4.z * m4.z + (1.f - m4.z) * (O[g][cg][2] * li4[2]);
      o4.w = q4.w * m4.w + (1.f - m4.w) * (O[g][cg][3] * li4[3]);
      *(float4*)(out + base) = o4;
    }
  }
}

extern "C" void kernel_launch(void* const* d_in, const int* in_sizes, int n_in,
                              void* d_out, int out_size, void* d_ws, size_t ws_size,
                              hipStream_t stream) {
  const float* queries = (const float*)d_in[0];
  const float* keys    = (const float*)d_in[1];
  const float* mask    = (const float*)d_in[2];
  const float* Wq = (const float*)d_in[3];
  const float* bq = (const float*)d_in[4];
  const float* Wk = (const float*)d_in[5];
  const float* bk = (const float*)d_in[6];
  const float* Wv = (const float*)d_in[7];
  const float* bv = (const float*)d_in[8];
  float* out = (float*)d_out;

  const size_t elems = (size_t)8 * NDIM * CDIM;
  _Float16* Qh = (_Float16*)d_ws;
  _Float16* Kh = Qh + elems;
  _Float16* Vh = Kh + elems;
  _Float16* Wc = Vh + elems;   // 3*65536 fp16

  cast_w_kernel<<<dim3(192), 256, 0, stream>>>(Wq, Wk, Wv, Wc);
  proj_kernel<<<dim3(32, 1, 24), 256, 0, stream>>>(
      queries, keys, Wc, bq, bk, bv, Qh, Kh, Vh);
  attn_kernel<<<dim3(512), 256, 0, stream>>>(
      queries, mask, Qh, Kh, Vh, out);
}